// Round 5
// baseline (296.322 us; speedup 1.0000x reference)
//
#include <hip/hip_runtime.h>
#include <hip/hip_bf16.h>
#include <math.h>

#define NN 2048
#define DA 256
#define DK 64
#define DG 64

typedef float f32x4 __attribute__((ext_vector_type(4)));

__device__ __forceinline__ float wave_reduce_max(float v) {
  #pragma unroll
  for (int o = 32; o >= 1; o >>= 1) v = fmaxf(v, __shfl_xor(v, o, 64));
  return v;
}
__device__ __forceinline__ float wave_reduce_sum(float v) {
  #pragma unroll
  for (int o = 32; o >= 1; o >>= 1) v += __shfl_xor(v, o, 64);
  return v;
}

// Allreduce-sum across each 16-lane row, pure VALU (DPP), no LDS pipe.
__device__ __forceinline__ float dpp_reduce16(float x) {
  int t;
  t = __builtin_amdgcn_update_dpp(0, __float_as_int(x), 0xB1, 0xF, 0xF, true);
  x += __int_as_float(t);
  t = __builtin_amdgcn_update_dpp(0, __float_as_int(x), 0x4E, 0xF, 0xF, true);
  x += __int_as_float(t);
  t = __builtin_amdgcn_update_dpp(0, __float_as_int(x), 0x124, 0xF, 0xF, true);
  x += __int_as_float(t);
  t = __builtin_amdgcn_update_dpp(0, __float_as_int(x), 0x128, 0xF, 0xF, true);
  x += __int_as_float(t);
  return x;
}

__device__ __forceinline__ float dot4(const f32x4 a, const f32x4 b) {
  float d = a.x * b.x;
  d = fmaf(a.y, b.y, d);
  d = fmaf(a.z, b.z, d);
  d = fmaf(a.w, b.w, d);
  return d;
}

// One block per row m: stage f_a row in LDS, 192 threads each compute one
// output element of {w_k, w_q, w_v}.
__global__ __launch_bounds__(256) void proj_kernel(
    const float* __restrict__ fa,
    const float* __restrict__ WKw, const float* __restrict__ WKb,
    const float* __restrict__ WQw, const float* __restrict__ WQb,
    const float* __restrict__ WVw, const float* __restrict__ WVb,
    float* __restrict__ wk, float* __restrict__ wq, float* __restrict__ wv)
{
  __shared__ float s_fa[DA];
  const int m = blockIdx.x, tid = threadIdx.x;
  s_fa[tid] = fa[(size_t)m * DA + tid];
  __syncthreads();
  if (tid < 192) {
    const int o = tid >> 6, k = tid & 63;
    const float* W = (o == 0 ? WKw : (o == 1 ? WQw : WVw)) + (size_t)k * DA;
    const float* B = (o == 0 ? WKb : (o == 1 ? WQb : WVb));
    float acc = B[k];
    const float4* W4 = (const float4*)W;
    const float4* F4 = (const float4*)s_fa;
    #pragma unroll 8
    for (int c = 0; c < DA / 4; ++c) {
      float4 w4 = W4[c], f4 = F4[c];
      acc = fmaf(w4.x, f4.x, acc); acc = fmaf(w4.y, f4.y, acc);
      acc = fmaf(w4.z, f4.z, acc); acc = fmaf(w4.w, f4.w, acc);
    }
    float* dst = (o == 0 ? wk : (o == 1 ? wq : wv));
    dst[(size_t)m * DK + k] = acc;
  }
}

// One block (256 threads = 4 waves) per output row m. Two-pass (round-3)
// structure; phase 1 widened to 8 n's per iteration (2x 1KB pe loads + 2x
// wq loads live per iter, unroll 4 -> up to 8KB pe in flight per wave).
__global__ __launch_bounds__(256) void fused_kernel(
    const float* __restrict__ pe,
    const float* __restrict__ wgw, const float* __restrict__ wgb,
    const float* __restrict__ wk, const float* __restrict__ wq,
    const float* __restrict__ wv,
    float* __restrict__ out)
{
  __shared__ float s_logit[NN];          // 8 KB: logits, then probs
  __shared__ float s_rmax[4], s_rsum[4];
  __shared__ float s_pacc[4][4][DK];     // 4 KB partial accumulators

  const int m = blockIdx.x, tid = threadIdx.x;
  const int wave = tid >> 6, lane = tid & 63;
  const int sub = lane >> 4;             // n within a 4-row chunk
  const int c4  = lane & 15;             // float4 chunk within 64 floats

  // loop-invariant per-lane slices
  const f32x4 wg4 = ((const f32x4*)wgw)[c4];
  const f32x4 wk4 = ((const f32x4*)(wk + (size_t)m * DK))[c4];
  const float gb = wgb[0];

  // ---- phase 1: logits (coalesced, 8 n's/iter, DPP allreduce) ----
  float lmax = -INFINITY;
  const int n0 = wave * (NN / 4);
  #pragma unroll 4
  for (int it = 0; it < (NN / 4) / 8; ++it) {   // 64 iters, 8 n's each
    const int nb = n0 + it * 8;
    const f32x4* peb = (const f32x4*)(pe + ((size_t)m * NN + nb) * DG);
    const f32x4* qb  = (const f32x4*)(wq + (size_t)nb * DK);
    const f32x4 pA = __builtin_nontemporal_load(peb + lane);
    const f32x4 pB = __builtin_nontemporal_load(peb + 64 + lane);
    const f32x4 qA = qb[lane];
    const f32x4 qB = qb[64 + lane];

    float dgA = dot4(pA, wg4), dqA = dot4(qA, wk4);
    float dgB = dot4(pB, wg4), dqB = dot4(qB, wk4);
    dgA = dpp_reduce16(dgA);
    dqA = dpp_reduce16(dqA);
    dgB = dpp_reduce16(dgB);
    dqB = dpp_reduce16(dqB);

    if (c4 == 0) {
      // relu -> clip(1e-6) -> log  ==  log(max(x, 1e-6))
      const float lA = __logf(fmaxf(dgA + gb, 1e-6f)) + dqA * 0.125f;
      const float lB = __logf(fmaxf(dgB + gb, 1e-6f)) + dqB * 0.125f;
      s_logit[nb + sub]     = lA;
      s_logit[nb + 4 + sub] = lB;
      lmax = fmaxf(lmax, fmaxf(lA, lB));
    }
  }
  lmax = wave_reduce_max(lmax);
  if (lane == 0) s_rmax[wave] = lmax;
  __syncthreads();
  const float rmax = fmaxf(fmaxf(s_rmax[0], s_rmax[1]), fmaxf(s_rmax[2], s_rmax[3]));

  // ---- phase 2: exp + sum ----
  float lsum = 0.f;
  #pragma unroll
  for (int i = 0; i < NN / 256; ++i) {
    const int n = i * 256 + tid;
    const float p = __expf(s_logit[n] - rmax);
    s_logit[n] = p;
    lsum += p;
  }
  lsum = wave_reduce_sum(lsum);
  if (lane == 0) s_rsum[wave] = lsum;
  __syncthreads();
  const float inv = 1.0f / (s_rsum[0] + s_rsum[1] + s_rsum[2] + s_rsum[3]);

  // ---- phase 3: out[m,:] = p-row @ w_v, float4 loads ----
  f32x4 acc = {0.f, 0.f, 0.f, 0.f};
  #pragma unroll 8
  for (int it = 0; it < (NN / 4) / 4; ++it) {
    const int nb = n0 + it * 4;
    const float pb = s_logit[nb + sub];
    const f32x4 v = ((const f32x4*)(wv + (size_t)(nb + sub) * DK))[c4];
    acc.x = fmaf(pb, v.x, acc.x);
    acc.y = fmaf(pb, v.y, acc.y);
    acc.z = fmaf(pb, v.z, acc.z);
    acc.w = fmaf(pb, v.w, acc.w);
  }
  ((f32x4*)&s_pacc[wave][sub][0])[c4] = acc;
  __syncthreads();
  if (tid < DK) {
    float r = 0.f;
    #pragma unroll
    for (int w = 0; w < 4; ++w)
      #pragma unroll
      for (int s = 0; s < 4; ++s)
        r += s_pacc[w][s][tid];
    out[(size_t)m * DK + tid] = r * inv;
  }
}

extern "C" void kernel_launch(void* const* d_in, const int* in_sizes, int n_in,
                              void* d_out, int out_size, void* d_ws, size_t ws_size,
                              hipStream_t stream) {
  const float* fa  = (const float*)d_in[0];
  const float* pe  = (const float*)d_in[1];
  const float* wgw = (const float*)d_in[2];
  const float* wgb = (const float*)d_in[3];
  const float* wkw = (const float*)d_in[4];
  const float* wkb = (const float*)d_in[5];
  const float* wqw = (const float*)d_in[6];
  const float* wqb = (const float*)d_in[7];
  const float* wvw = (const float*)d_in[8];
  const float* wvb = (const float*)d_in[9];
  float* out = (float*)d_out;

  float* wk = (float*)d_ws;          // [NN, DK]
  float* wq = wk + (size_t)NN * DK;  // [NN, DK]
  float* wv = wq + (size_t)NN * DK;  // [NN, DK]

  proj_kernel<<<NN, 256, 0, stream>>>(fa, wkw, wkb, wqw, wqb, wvw, wvb, wk, wq, wv);
  fused_kernel<<<NN, 256, 0, stream>>>(pe, wgw, wgb, wk, wq, wv, out);
}

// Round 6
// 280.910 us; speedup vs baseline: 1.0549x; 1.0549x over previous
//
#include <hip/hip_runtime.h>
#include <hip/hip_bf16.h>
#include <math.h>

#define NN 2048
#define DA 256
#define DK 64
#define DG 64
#define MROWS 4

typedef float f32x4 __attribute__((ext_vector_type(4)));

__device__ __forceinline__ float wave_reduce_max(float v) {
  #pragma unroll
  for (int o = 32; o >= 1; o >>= 1) v = fmaxf(v, __shfl_xor(v, o, 64));
  return v;
}
__device__ __forceinline__ float wave_reduce_sum(float v) {
  #pragma unroll
  for (int o = 32; o >= 1; o >>= 1) v += __shfl_xor(v, o, 64);
  return v;
}

// Allreduce-sum across each 16-lane row, pure VALU (DPP).
__device__ __forceinline__ float dpp_reduce16(float x) {
  int t;
  t = __builtin_amdgcn_update_dpp(0, __float_as_int(x), 0xB1, 0xF, 0xF, true);
  x += __int_as_float(t);
  t = __builtin_amdgcn_update_dpp(0, __float_as_int(x), 0x4E, 0xF, 0xF, true);
  x += __int_as_float(t);
  t = __builtin_amdgcn_update_dpp(0, __float_as_int(x), 0x124, 0xF, 0xF, true);
  x += __int_as_float(t);
  t = __builtin_amdgcn_update_dpp(0, __float_as_int(x), 0x128, 0xF, 0xF, true);
  x += __int_as_float(t);
  return x;
}

__device__ __forceinline__ float dot4(const f32x4 a, const f32x4 b) {
  float d = a.x * b.x;
  d = fmaf(a.y, b.y, d);
  d = fmaf(a.z, b.z, d);
  d = fmaf(a.w, b.w, d);
  return d;
}

// One block per row m: stage f_a row in LDS, 192 threads each compute one
// output element of {w_k, w_q, w_v}.
__global__ __launch_bounds__(256) void proj_kernel(
    const float* __restrict__ fa,
    const float* __restrict__ WKw, const float* __restrict__ WKb,
    const float* __restrict__ WQw, const float* __restrict__ WQb,
    const float* __restrict__ WVw, const float* __restrict__ WVb,
    float* __restrict__ wk, float* __restrict__ wq, float* __restrict__ wv)
{
  __shared__ float s_fa[DA];
  const int m = blockIdx.x, tid = threadIdx.x;
  s_fa[tid] = fa[(size_t)m * DA + tid];
  __syncthreads();
  if (tid < 192) {
    const int o = tid >> 6, k = tid & 63;
    const float* W = (o == 0 ? WKw : (o == 1 ? WQw : WVw)) + (size_t)k * DA;
    const float* B = (o == 0 ? WKb : (o == 1 ? WQb : WVb));
    float acc = B[k];
    const float4* W4 = (const float4*)W;
    const float4* F4 = (const float4*)s_fa;
    #pragma unroll 8
    for (int c = 0; c < DA / 4; ++c) {
      float4 w4 = W4[c], f4 = F4[c];
      acc = fmaf(w4.x, f4.x, acc); acc = fmaf(w4.y, f4.y, acc);
      acc = fmaf(w4.z, f4.z, acc); acc = fmaf(w4.w, f4.w, acc);
    }
    float* dst = (o == 0 ? wk : (o == 1 ? wq : wv));
    dst[(size_t)m * DK + k] = acc;
  }
}

// One block (256 threads = 4 waves) per 4 output rows m0..m0+3.
// Pre-phase: all QK scores for the 4 rows -> s_sc (register-blocked dots).
// Phase 1:   stream pe for 4 rows; per 4KB only 4 dot4 + 4 DPP reduces;
//            logit = log(max(pe.wg+gb,1e-6)) added into s_sc.
// Phase 2:   wave w softmaxes row w (wave-private).
// Phase 3:   each wv float4 loaded once, used for all 4 rows.
__global__ __launch_bounds__(256) void fused_kernel(
    const float* __restrict__ pe,
    const float* __restrict__ wgw, const float* __restrict__ wgb,
    const float* __restrict__ wk, const float* __restrict__ wq,
    const float* __restrict__ wv,
    float* __restrict__ out)
{
  __shared__ float s_sc[MROWS][NN];        // 32 KB: scores -> logits -> probs
  __shared__ float s_pacc[4][MROWS][DK];   // 4 KB partials
  __shared__ float s_rsum[MROWS];

  const int m0 = blockIdx.x * MROWS;
  const int tid = threadIdx.x;
  const int wave = tid >> 6, lane = tid & 63;
  const int sub = lane >> 4;               // n within a 4-n chunk
  const int c4  = lane & 15;               // float4 chunk within 64 floats

  // ---- pre-phase: s_sc[i][n] = 0.125 * (wk[m0+i] . wq[n]) ----
  {
    float acc[8][MROWS];
    #pragma unroll
    for (int j = 0; j < 8; ++j)
      #pragma unroll
      for (int i = 0; i < MROWS; ++i) acc[j][i] = 0.f;
    #pragma unroll 4
    for (int c = 0; c < DK / 4; ++c) {
      f32x4 wkc[MROWS];
      #pragma unroll
      for (int i = 0; i < MROWS; ++i)
        wkc[i] = ((const f32x4*)(wk + (size_t)(m0 + i) * DK))[c];
      #pragma unroll
      for (int j = 0; j < 8; ++j) {
        const int n = j * 256 + tid;
        const f32x4 q = ((const f32x4*)(wq + (size_t)n * DK))[c];
        #pragma unroll
        for (int i = 0; i < MROWS; ++i) {
          acc[j][i] = fmaf(q.x, wkc[i].x, acc[j][i]);
          acc[j][i] = fmaf(q.y, wkc[i].y, acc[j][i]);
          acc[j][i] = fmaf(q.z, wkc[i].z, acc[j][i]);
          acc[j][i] = fmaf(q.w, wkc[i].w, acc[j][i]);
        }
      }
    }
    #pragma unroll
    for (int j = 0; j < 8; ++j) {
      const int n = j * 256 + tid;
      #pragma unroll
      for (int i = 0; i < MROWS; ++i)
        s_sc[i][n] = acc[j][i] * 0.125f;
    }
  }
  __syncthreads();

  // ---- phase 1: geometric term, 4 pe streams ----
  const f32x4 wg4 = ((const f32x4*)wgw)[c4];
  const float gb = wgb[0];
  const int n0w = wave * (NN / 4);
  #pragma unroll 2
  for (int it = 0; it < (NN / 4) / 4; ++it) {   // 128 iters, 4 n x 4 rows
    const int nb = n0w + it * 4;
    f32x4 p[MROWS];
    #pragma unroll
    for (int i = 0; i < MROWS; ++i)
      p[i] = __builtin_nontemporal_load(
          (const f32x4*)(pe + ((size_t)(m0 + i) * NN + nb) * DG) + lane);
    #pragma unroll
    for (int i = 0; i < MROWS; ++i) {
      float dg = dot4(p[i], wg4);
      dg = dpp_reduce16(dg);
      if (c4 == 0) {
        // relu -> clip(1e-6) -> log  ==  log(max(x, 1e-6))
        s_sc[i][nb + sub] += __logf(fmaxf(dg + gb, 1e-6f));
      }
    }
  }
  __syncthreads();

  // ---- phase 2: per-row softmax, wave w owns row w ----
  {
    float mx = -INFINITY;
    #pragma unroll
    for (int j = 0; j < NN / 64; ++j)
      mx = fmaxf(mx, s_sc[wave][j * 64 + lane]);
    mx = wave_reduce_max(mx);
    float sm = 0.f;
    #pragma unroll
    for (int j = 0; j < NN / 64; ++j) {
      const float pr = __expf(s_sc[wave][j * 64 + lane] - mx);
      s_sc[wave][j * 64 + lane] = pr;
      sm += pr;
    }
    sm = wave_reduce_sum(sm);
    if (lane == 0) s_rsum[wave] = sm;
  }
  __syncthreads();

  // ---- phase 3: out = probs @ wv, each v-vector used for 4 rows ----
  f32x4 vacc[MROWS];
  #pragma unroll
  for (int i = 0; i < MROWS; ++i) vacc[i] = (f32x4){0.f, 0.f, 0.f, 0.f};
  #pragma unroll 4
  for (int it = 0; it < (NN / 4) / 4; ++it) {
    const int n = n0w + it * 4 + sub;
    const f32x4 v = ((const f32x4*)(wv + (size_t)n * DK))[c4];
    #pragma unroll
    for (int i = 0; i < MROWS; ++i) {
      const float pr = s_sc[i][n];
      vacc[i].x = fmaf(pr, v.x, vacc[i].x);
      vacc[i].y = fmaf(pr, v.y, vacc[i].y);
      vacc[i].z = fmaf(pr, v.z, vacc[i].z);
      vacc[i].w = fmaf(pr, v.w, vacc[i].w);
    }
  }
  #pragma unroll
  for (int i = 0; i < MROWS; ++i) {
    vacc[i].x += __shfl_xor(vacc[i].x, 16, 64); vacc[i].x += __shfl_xor(vacc[i].x, 32, 64);
    vacc[i].y += __shfl_xor(vacc[i].y, 16, 64); vacc[i].y += __shfl_xor(vacc[i].y, 32, 64);
    vacc[i].z += __shfl_xor(vacc[i].z, 16, 64); vacc[i].z += __shfl_xor(vacc[i].z, 32, 64);
    vacc[i].w += __shfl_xor(vacc[i].w, 16, 64); vacc[i].w += __shfl_xor(vacc[i].w, 32, 64);
  }
  if (lane < 16) {
    #pragma unroll
    for (int i = 0; i < MROWS; ++i)
      ((f32x4*)s_pacc[wave][i])[c4] = vacc[i];
  }
  __syncthreads();
  {
    const int i = tid >> 6, k = tid & 63;
    const float r = s_pacc[0][i][k] + s_pacc[1][i][k] +
                    s_pacc[2][i][k] + s_pacc[3][i][k];
    out[(size_t)(m0 + i) * DK + k] = r / s_rsum[i];
  }
}

extern "C" void kernel_launch(void* const* d_in, const int* in_sizes, int n_in,
                              void* d_out, int out_size, void* d_ws, size_t ws_size,
                              hipStream_t stream) {
  const float* fa  = (const float*)d_in[0];
  const float* pe  = (const float*)d_in[1];
  const float* wgw = (const float*)d_in[2];
  const float* wgb = (const float*)d_in[3];
  const float* wkw = (const float*)d_in[4];
  const float* wkb = (const float*)d_in[5];
  const float* wqw = (const float*)d_in[6];
  const float* wqb = (const float*)d_in[7];
  const float* wvw = (const float*)d_in[8];
  const float* wvb = (const float*)d_in[9];
  float* out = (float*)d_out;

  float* wk = (float*)d_ws;          // [NN, DK]
  float* wq = wk + (size_t)NN * DK;  // [NN, DK]
  float* wv = wq + (size_t)NN * DK;  // [NN, DK]

  proj_kernel<<<NN, 256, 0, stream>>>(fa, wkw, wkb, wqw, wqb, wvw, wvb, wk, wq, wv);
  fused_kernel<<<NN / MROWS, 256, 0, stream>>>(pe, wgw, wgb, wk, wq, wv, out);
}